// Round 1
// baseline (106.714 us; speedup 1.0000x reference)
//
#include <hip/hip_runtime.h>

// Speculative-decode next-step input preparation.
// Per request r (R=8192), T = 1+SPEC = 8 tokens:
//   a        = clamp(accepted_num[r], 1, SC)
//   base     = input_positions[r*T] + a
//   pos[j]   = base + j
//   tok[0]   = sampled_tokens[r, a-1]; tok[j>0] = spec_tokens[r, j-1]
//   blk      = block_table[r, pos/block_size]
//   slot     = blk*block_size + pos%block_size
//   seq_len  = pos + 1
// Outputs concatenated flat: [tokens | pos | seq_lens | slots], each R*T int32.
//
// v2: token-parallel fast path. The old request-parallel kernel launched only
// 8192 threads = 32 workgroups = 128 waves -> <=32 of 256 CUs active, and the
// depth-2 dependent-load chain (inputs -> base -> 64MiB block_table gather,
// ~900cy L2-miss) had almost no TLP to hide under. One thread per TOKEN gives
// 65536 threads = 256 WGs = 1024 waves (4/CU, whole chip), same chain depth,
// 8x the memory-level parallelism. The 8 lanes of one request share cachelines
// for p/a/block_table, so redundant loads coalesce in L1/L2.

__global__ __launch_bounds__(256) void spec_prep_t8_tok_kernel(
    const int* __restrict__ input_positions,   // [R*8]
    const int* __restrict__ sampled_tokens,    // [R*8]  (SC==8)
    const int* __restrict__ block_table,       // [R*MAXB]
    const int* __restrict__ spec_tokens,       // [R*7]
    const int* __restrict__ accepted_num,      // [R]
    const int* __restrict__ block_size_p,      // [1]
    int* __restrict__ out,                     // [4*N]
    int MAXB, int N)
{
    const int idx = blockIdx.x * blockDim.x + threadIdx.x;
    if (idx >= N) return;
    const int j = idx & 7;
    const int r = idx >> 3;

    const int bs = *block_size_p;              // uniform s_load

    // Independent first-level loads, all issued up front.
    const int p     = input_positions[idx & ~7];   // 8 lanes/request broadcast
    const int a_raw = accepted_num[r];

    int a = a_raw < 1 ? 1 : (a_raw > 8 ? 8 : a_raw);

    // token: lane j==0 gathers last accepted sample, j>0 read draft tokens
    int tok;
    if (j == 0) {
        tok = sampled_tokens[r * 8 + (a - 1)];
    } else {
        tok = spec_tokens[r * 7 + (j - 1)];
    }

    // second-level: block table gather (runs concurrently with tok gather)
    const int pos = p + a + j;
    const int d   = pos / bs;
    const int blk = block_table[(long)r * MAXB + d];
    const int slot = blk * bs + (pos - d * bs);

    out[idx]         = tok;
    out[N + idx]     = pos;
    out[2 * N + idx] = pos + 1;
    out[3 * N + idx] = slot;
}

// Generic fallback (any T): 1 thread per output element.
__global__ __launch_bounds__(256) void spec_prep_generic_kernel(
    const int* __restrict__ input_positions,
    const int* __restrict__ sampled_tokens,
    const int* __restrict__ block_table,
    const int* __restrict__ spec_tokens,
    const int* __restrict__ accepted_num,
    const int* __restrict__ block_size_p,
    int* __restrict__ out,
    int T, int SC, int SPEC, int MAXB, int N)
{
    int idx = blockIdx.x * blockDim.x + threadIdx.x;
    if (idx >= N) return;
    int r = idx / T;
    int j = idx - r * T;
    int bs = *block_size_p;
    int a = accepted_num[r];
    a = a < 1 ? 1 : (a > SC ? SC : a);
    int pos = input_positions[r * T] + a + j;
    int tok = (j == 0) ? sampled_tokens[r * SC + (a - 1)]
                       : spec_tokens[r * SPEC + (j - 1)];
    int blk = block_table[(long)r * MAXB + pos / bs];
    out[idx]         = tok;
    out[N + idx]     = pos;
    out[2 * N + idx] = pos + 1;
    out[3 * N + idx] = blk * bs + pos % bs;
}

extern "C" void kernel_launch(void* const* d_in, const int* in_sizes, int n_in,
                              void* d_out, int out_size, void* d_ws, size_t ws_size,
                              hipStream_t stream) {
    // setup_inputs() order:
    // 0 input_tokens (unused), 1 sampled_tokens [R*SC], 2 input_positions [R*T],
    // 3 seq_lens (unused), 4 slot_mapping (unused), 5 block_table [R*MAXB],
    // 6 spec_tokens [R*SPEC], 7 accepted_num [R], 8 num_seqs, 9 num_queries, 10 block_size
    const int* sampled_tokens  = (const int*)d_in[1];
    const int* input_positions = (const int*)d_in[2];
    const int* block_table     = (const int*)d_in[5];
    const int* spec_tokens     = (const int*)d_in[6];
    const int* accepted_num    = (const int*)d_in[7];
    const int* block_size_p    = (const int*)d_in[10];

    const int R    = in_sizes[7];
    const int N    = in_sizes[2];          // R*T
    const int T    = N / R;
    const int SC   = in_sizes[1] / R;
    const int SPEC = in_sizes[6] / R;
    const int MAXB = in_sizes[5] / R;

    int* out = (int*)d_out;

    if (T == 8 && SPEC == 7 && SC == 8) {
        const int block = 256;
        const int grid = (N + block - 1) / block;   // 256 workgroups, 1024 waves
        spec_prep_t8_tok_kernel<<<grid, block, 0, stream>>>(
            input_positions, sampled_tokens, block_table, spec_tokens,
            accepted_num, block_size_p, out, MAXB, N);
    } else {
        const int block = 256;
        const int grid = (N + block - 1) / block;
        spec_prep_generic_kernel<<<grid, block, 0, stream>>>(
            input_positions, sampled_tokens, block_table, spec_tokens,
            accepted_num, block_size_p, out, T, SC, SPEC, MAXB, N);
    }
}